// Round 1
// baseline (1179.777 us; speedup 1.0000x reference)
//
#include <hip/hip_runtime.h>
#include <hip/hip_bf16.h>
#include <math.h>

// Problem constants
#define BB 8
#define TT 1024
#define CC 768
#define HH 12
#define HD 64
#define MM (BB*TT)          // 8192 rows
#define NELT (MM*CC)        // 6291456 elements per output tensor

// ---------------------------------------------------------------------------
// GEMM: out = A @ W^T.  A: (M,768) row-major, W: (N,768) row-major.
// 64x64 tile, BK=32, 256 threads, 4x4 register micro-tile.
// LDS tiles stored k-major (As[kk][m]) so the inner loop reads float4
// (ds_read_b128) per operand. Row stride 68 floats = 272B (16B-aligned, and
// breaks the power-of-2 bank stride).
// QKV=true scatters output to (B,H,T,Hd) layout.
// ---------------------------------------------------------------------------
template <bool QKV>
__device__ __forceinline__ void gemm_body(const float* __restrict__ A,
                                          const float* __restrict__ W,
                                          float* __restrict__ out)
{
    __shared__ float As[32][68];
    __shared__ float Bs[32][68];

    const int tid  = threadIdx.x;
    const int bm   = blockIdx.x, bn = blockIdx.y;
    const int tm   = tid >> 4;          // 0..15
    const int tn   = tid & 15;          // 0..15
    const int row0 = bm * 64, col0 = bn * 64;

    const int lr = tid >> 3;            // 0..31 (load row, +32 for second half)
    const int lc = (tid & 7) << 2;      // 0,4,...,28 (k offset)

    float acc[4][4] = {};

    for (int k0 = 0; k0 < CC; k0 += 32) {
        __syncthreads();
        const float4 a0 = *(const float4*)&A[(row0 + lr)      * CC + k0 + lc];
        const float4 a1 = *(const float4*)&A[(row0 + lr + 32) * CC + k0 + lc];
        const float4 b0 = *(const float4*)&W[(col0 + lr)      * CC + k0 + lc];
        const float4 b1 = *(const float4*)&W[(col0 + lr + 32) * CC + k0 + lc];
        As[lc+0][lr] = a0.x; As[lc+1][lr] = a0.y; As[lc+2][lr] = a0.z; As[lc+3][lr] = a0.w;
        As[lc+0][lr+32] = a1.x; As[lc+1][lr+32] = a1.y; As[lc+2][lr+32] = a1.z; As[lc+3][lr+32] = a1.w;
        Bs[lc+0][lr] = b0.x; Bs[lc+1][lr] = b0.y; Bs[lc+2][lr] = b0.z; Bs[lc+3][lr] = b0.w;
        Bs[lc+0][lr+32] = b1.x; Bs[lc+1][lr+32] = b1.y; Bs[lc+2][lr+32] = b1.z; Bs[lc+3][lr+32] = b1.w;
        __syncthreads();

#pragma unroll
        for (int kk = 0; kk < 32; ++kk) {
            const float4 av = *(const float4*)&As[kk][tm << 2];
            const float4 bv = *(const float4*)&Bs[kk][tn << 2];
            const float a_[4] = {av.x, av.y, av.z, av.w};
            const float b_[4] = {bv.x, bv.y, bv.z, bv.w};
#pragma unroll
            for (int i = 0; i < 4; ++i)
#pragma unroll
                for (int j = 0; j < 4; ++j)
                    acc[i][j] = fmaf(a_[i], b_[j], acc[i][j]);
        }
    }

#pragma unroll
    for (int i = 0; i < 4; ++i) {
        float4 r;
        r.x = acc[i][0]; r.y = acc[i][1]; r.z = acc[i][2]; r.w = acc[i][3];
        const int m = row0 + (tm << 2) + i;
        if (QKV) {
            const int b = m >> 10, t = m & 1023;
            const int h = col0 >> 6;                 // col0 is a multiple of 64
            *(float4*)&out[(((b * HH + h) << 10) | t) * HD + (tn << 2)] = r;
        } else {
            *(float4*)&out[m * CC + col0 + (tn << 2)] = r;
        }
    }
}

__global__ __launch_bounds__(256)
void gemm_qkv_kernel(const float* __restrict__ A,
                     const float* __restrict__ Wq, const float* __restrict__ Wk,
                     const float* __restrict__ Wv,
                     float* __restrict__ q, float* __restrict__ k, float* __restrict__ v)
{
    const float* W = (blockIdx.z == 0) ? Wq : (blockIdx.z == 1) ? Wk : Wv;
    float*       o = (blockIdx.z == 0) ? q  : (blockIdx.z == 1) ? k  : v;
    gemm_body<true>(A, W, o);
}

__global__ __launch_bounds__(256)
void gemm_out_kernel(const float* __restrict__ A, const float* __restrict__ Wo,
                     float* __restrict__ out)
{
    gemm_body<false>(A, Wo, out);
}

// ---------------------------------------------------------------------------
// RoPE + QK RMSNorm, in place. One wave (64 lanes) per (b,h,t) row; the head
// dim (64) maps 1:1 to lanes, partner element via shfl_xor(32), RMS via
// full-wave butterfly reduce.
// ---------------------------------------------------------------------------
__global__ __launch_bounds__(256)
void rope_qknorm_kernel(float* __restrict__ q, float* __restrict__ k)
{
    const int row  = blockIdx.x * 4 + (threadIdx.x >> 6);   // (b*H+h)*T + t
    const int lane = threadIdx.x & 63;
    const int t    = row & (TT - 1);

    float qv = q[row * HD + lane];
    float kv = k[row * HD + lane];

    const int d = lane & 31;
    const float fr = (float)t * powf(10000.f, -(float)d * (1.f / 32.f));
    const float c = cosf(fr), s = sinf(fr);

    const float qp = __shfl_xor(qv, 32);
    const float kp = __shfl_xor(kv, 32);

    float qo, ko;
    if (lane < 32) { qo = qv * c - qp * s;  ko = kv * c - kp * s; }
    else           { qo = qp * s + qv * c;  ko = kp * s + kv * c; }

    float qs = qo * qo, ks = ko * ko;
#pragma unroll
    for (int m = 1; m < 64; m <<= 1) {
        qs += __shfl_xor(qs, m);
        ks += __shfl_xor(ks, m);
    }
    qo *= rsqrtf(qs * (1.f / 64.f) + 1e-6f);
    ko *= rsqrtf(ks * (1.f / 64.f) + 1e-6f);

    q[row * HD + lane] = qo;
    k[row * HD + lane] = ko;
}

// ---------------------------------------------------------------------------
// Flash-style causal attention, f32.
// Block = 256 threads handles one (b,h) and a 32-row Q tile.
// Thread (r = tid>>3, c8 = tid&7): owns 8 score columns (j = jj*8+c8) in the
// QK phase and 8 output dims (d = c8*8+i) in the PV phase.
// Online softmax state (m,l) replicated across the 8 lanes of a row (they
// compute identical reduced values via 3-step shfl_xor within the row group).
// K/V chunks of 64 rows staged in LDS; causal limit skips ~half the chunks.
// ---------------------------------------------------------------------------
__global__ __launch_bounds__(256)
void attn_kernel(const float* __restrict__ q, const float* __restrict__ k,
                 const float* __restrict__ v, float* __restrict__ y)
{
    const int qt  = blockIdx.x;       // 0..31
    const int bh  = blockIdx.y;       // 0..95
    const int tid = threadIdx.x;
    const int r   = tid >> 3;         // 0..31 (q row in tile)
    const int c8  = tid & 7;          // 0..7

    __shared__ float Qs[32][68];
    __shared__ float Ks[64][68];
    __shared__ float Vs[64][68];
    __shared__ float Ss[32][66];

    const float* qb = q + (bh * TT + qt * 32) * HD;
    const float* kb = k + bh * TT * HD;
    const float* vb = v + bh * TT * HD;

    // load Q tile (32x64) as float4
    for (int e = tid; e < 512; e += 256) {
        const int row = e >> 4, dd = (e & 15) << 2;
        *(float4*)&Qs[row][dd] = *(const float4*)&qb[row * HD + dd];
    }

    float acc[8] = {};
    float mrow = -1e30f, lrow = 0.f;
    const int qglob = qt * 32 + r;
    const int ktmax = (qt * 32 + 31) >> 6;

    for (int kt = 0; kt <= ktmax; ++kt) {
        __syncthreads();
        for (int e = tid; e < 1024; e += 256) {
            const int row = e >> 4, dd = (e & 15) << 2;
            *(float4*)&Ks[row][dd] = *(const float4*)&kb[kt * 4096 + row * HD + dd];
            *(float4*)&Vs[row][dd] = *(const float4*)&vb[kt * 4096 + row * HD + dd];
        }
        __syncthreads();

        // scores for this thread's 8 columns
        float sv[8];
        float cmax = -1e30f;
#pragma unroll
        for (int jj = 0; jj < 8; ++jj) {
            const int j = (jj << 3) + c8;
            float dot = 0.f;
#pragma unroll
            for (int d4 = 0; d4 < 16; ++d4) {
                const float4 qv4 = *(const float4*)&Qs[r][d4 << 2];
                const float4 kv4 = *(const float4*)&Ks[j][d4 << 2];
                dot = fmaf(qv4.x, kv4.x, dot);
                dot = fmaf(qv4.y, kv4.y, dot);
                dot = fmaf(qv4.z, kv4.z, dot);
                dot = fmaf(qv4.w, kv4.w, dot);
            }
            const int kc = (kt << 6) + j;
            sv[jj] = (kc <= qglob) ? dot * 0.125f : -1e30f;
            cmax = fmaxf(cmax, sv[jj]);
        }
        // row max across the 8 lanes of this row
        cmax = fmaxf(cmax, __shfl_xor(cmax, 1));
        cmax = fmaxf(cmax, __shfl_xor(cmax, 2));
        cmax = fmaxf(cmax, __shfl_xor(cmax, 4));

        const float mnew   = fmaxf(mrow, cmax);
        const float factor = __expf(mrow - mnew);
        float csum = 0.f;
#pragma unroll
        for (int jj = 0; jj < 8; ++jj) {
            const float p = __expf(sv[jj] - mnew);
            Ss[r][(jj << 3) + c8] = p;
            csum += p;
        }
        csum += __shfl_xor(csum, 1);
        csum += __shfl_xor(csum, 2);
        csum += __shfl_xor(csum, 4);
        lrow = lrow * factor + csum;
        mrow = mnew;
#pragma unroll
        for (int i = 0; i < 8; ++i) acc[i] *= factor;
        __syncthreads();

        // PV: acc[d] += sum_j p[j] * V[j][d], d = c8*8 + i
#pragma unroll
        for (int j = 0; j < 64; ++j) {
            const float p = Ss[r][j];
            const float4 v0 = *(const float4*)&Vs[j][(c8 << 3)];
            const float4 v1 = *(const float4*)&Vs[j][(c8 << 3) + 4];
            acc[0] = fmaf(p, v0.x, acc[0]);
            acc[1] = fmaf(p, v0.y, acc[1]);
            acc[2] = fmaf(p, v0.z, acc[2]);
            acc[3] = fmaf(p, v0.w, acc[3]);
            acc[4] = fmaf(p, v1.x, acc[4]);
            acc[5] = fmaf(p, v1.y, acc[5]);
            acc[6] = fmaf(p, v1.z, acc[6]);
            acc[7] = fmaf(p, v1.w, acc[7]);
        }
    }

    const int b = bh / HH, h = bh % HH;
    const float inv_l = 1.f / lrow;
    float* yr = y + (b * TT + qglob) * CC + h * HD + (c8 << 3);
    float4 o0, o1;
    o0.x = acc[0] * inv_l; o0.y = acc[1] * inv_l; o0.z = acc[2] * inv_l; o0.w = acc[3] * inv_l;
    o1.x = acc[4] * inv_l; o1.y = acc[5] * inv_l; o1.z = acc[6] * inv_l; o1.w = acc[7] * inv_l;
    *(float4*)&yr[0] = o0;
    *(float4*)&yr[4] = o1;
}

// ---------------------------------------------------------------------------
extern "C" void kernel_launch(void* const* d_in, const int* in_sizes, int n_in,
                              void* d_out, int out_size, void* d_ws, size_t ws_size,
                              hipStream_t stream)
{
    (void)in_sizes; (void)n_in; (void)out_size; (void)ws_size;
    const float* x  = (const float*)d_in[0];
    const float* Wq = (const float*)d_in[1];
    const float* Wk = (const float*)d_in[2];
    const float* Wv = (const float*)d_in[3];
    const float* Wo = (const float*)d_in[4];

    float* y_out = (float*)d_out;            // (B,T,C)
    float* k_out = y_out + NELT;             // (B,H,T,Hd)
    float* v_out = k_out + NELT;             // (B,H,T,Hd)

    float* q_ws = (float*)d_ws;              // (B,H,T,Hd)
    float* y_ws = q_ws + NELT;               // (B,T,C) attention output pre-Wo

    gemm_qkv_kernel<<<dim3(MM/64, CC/64, 3), 256, 0, stream>>>(x, Wq, Wk, Wv, q_ws, k_out, v_out);
    rope_qknorm_kernel<<<dim3((BB*HH*TT)/4), 256, 0, stream>>>(q_ws, k_out);
    attn_kernel<<<dim3(TT/32, BB*HH), 256, 0, stream>>>(q_ws, k_out, v_out, y_ws);
    gemm_out_kernel<<<dim3(MM/64, CC/64), 256, 0, stream>>>(y_ws, Wo, y_out);
}

// Round 3
// 395.753 us; speedup vs baseline: 2.9811x; 2.9811x over previous
//
#include <hip/hip_runtime.h>
#include <hip/hip_bf16.h>
#include <math.h>

// Problem constants
#define BB 8
#define TT 1024
#define CC 768
#define HH 12
#define HD 64
#define MM (BB*TT)           // 8192 rows
#define NELT (MM*CC)         // 6291456 elements per tensor

typedef short bf16x8 __attribute__((ext_vector_type(8)));   // 8 bf16 = 4 VGPR
typedef float f32x4  __attribute__((ext_vector_type(4)));   // MFMA accum

__device__ __forceinline__ short f2bf(float f) {
    union { float f; unsigned u; } a; a.f = f;
    unsigned r = a.u + 0x7fffu + ((a.u >> 16) & 1u);        // RNE
    return (short)(r >> 16);
}
__device__ __forceinline__ float bf2f(short s) {
    union { unsigned u; float f; } a; a.u = ((unsigned)(unsigned short)s) << 16;
    return a.f;
}

// ---------------------------------------------------------------------------
// bf16 MFMA GEMM core: C[128,128] tile of A[M,768] @ W[N,768]^T.
// 256 threads = 4 waves in 2x2 grid, each wave 64x64 out = 4x4 frags 16x16.
// Reg-staged (global f32 -> cvt -> LDS bf16); LDS rows padded to 40 shorts
// (80B) so frag ds_read_b128 is <=2-way per quarter-wave.
// A_BF16: A already bf16 in global (attention output path).
// ---------------------------------------------------------------------------
template<bool A_BF16>
__device__ __forceinline__ void gemm_core(const void* __restrict__ A_,
                                          const float* __restrict__ W,
                                          int row0, int col0,
                                          f32x4 acc[4][4])
{
    __shared__ short As[128][40];
    __shared__ short Bs[128][40];
    const int tid  = threadIdx.x;
    const int lane = tid & 63;
    const int wid  = tid >> 6;
    const int wr   = (wid >> 1) * 64;
    const int wc   = (wid & 1) * 64;
    const int fr   = lane & 15;      // fragment row (A row / B col / D col)
    const int fg   = lane >> 4;      // k-group: k = fg*8..fg*8+7; D rows fg*4+j

    for (int k0 = 0; k0 < 768; k0 += 32) {
        __syncthreads();
        if (A_BF16) {
            const short* A = (const short*)A_;
#pragma unroll
            for (int i = 0; i < 2; ++i) {
                const int flat = i * 256 + tid;          // 16B chunk id (512 total)
                const int row = flat >> 2, c8 = (flat & 3) * 8;
                *(int4*)&As[row][c8] =
                    *(const int4*)&A[(size_t)(row0 + row) * 768 + k0 + c8];
            }
        } else {
            const float* A = (const float*)A_;
#pragma unroll
            for (int i = 0; i < 4; ++i) {
                const int flat = i * 256 + tid;          // float4 id (1024 total)
                const int row = flat >> 3, c4 = (flat & 7) * 4;
                const float4 v = *(const float4*)&A[(size_t)(row0 + row) * 768 + k0 + c4];
                short4 h;
                h.x = f2bf(v.x); h.y = f2bf(v.y); h.z = f2bf(v.z); h.w = f2bf(v.w);
                *(short4*)&As[row][c4] = h;
            }
        }
#pragma unroll
        for (int i = 0; i < 4; ++i) {
            const int flat = i * 256 + tid;
            const int row = flat >> 3, c4 = (flat & 7) * 4;
            const float4 v = *(const float4*)&W[(size_t)(col0 + row) * 768 + k0 + c4];
            short4 h;
            h.x = f2bf(v.x); h.y = f2bf(v.y); h.z = f2bf(v.z); h.w = f2bf(v.w);
            *(short4*)&Bs[row][c4] = h;
        }
        __syncthreads();

        bf16x8 a[4], b[4];
#pragma unroll
        for (int m = 0; m < 4; ++m)
            a[m] = *(const bf16x8*)&As[wr + m*16 + fr][fg*8];
#pragma unroll
        for (int n = 0; n < 4; ++n)
            b[n] = *(const bf16x8*)&Bs[wc + n*16 + fr][fg*8];
#pragma unroll
        for (int m = 0; m < 4; ++m)
#pragma unroll
            for (int n = 0; n < 4; ++n)
                acc[m][n] = __builtin_amdgcn_mfma_f32_16x16x32_bf16(a[m], b[n], acc[m][n], 0, 0, 0);
    }
}

// QKV projection: z=0 -> q bf16 (ws), z=1 -> k f32 (d_out), z=2 -> v f32 + bf16.
// Output layout (B,H,T,Hd): row m -> (b,t), col -> (h,hd).
__global__ __launch_bounds__(256)
void gemm_qkv(const float* __restrict__ x,
              const float* __restrict__ Wq, const float* __restrict__ Wk,
              const float* __restrict__ Wv,
              short* __restrict__ qb, float* __restrict__ kf,
              float* __restrict__ vf, short* __restrict__ vb)
{
    const int z = blockIdx.z;
    const float* W = (z == 0) ? Wq : (z == 1) ? Wk : Wv;
    const int row0 = blockIdx.x * 128, col0 = blockIdx.y * 128;

    f32x4 acc[4][4];
#pragma unroll
    for (int m = 0; m < 4; ++m)
#pragma unroll
        for (int n = 0; n < 4; ++n) acc[m][n] = (f32x4){0.f, 0.f, 0.f, 0.f};

    gemm_core<false>(x, W, row0, col0, acc);

    const int lane = threadIdx.x & 63, wid = threadIdx.x >> 6;
    const int fr = lane & 15, fg = lane >> 4;
#pragma unroll
    for (int m = 0; m < 4; ++m) {
#pragma unroll
        for (int j = 0; j < 4; ++j) {
            const int row = row0 + (wid >> 1) * 64 + m * 16 + fg * 4 + j;
            const int b = row >> 10, t = row & 1023;
#pragma unroll
            for (int n = 0; n < 4; ++n) {
                const int col = col0 + (wid & 1) * 64 + n * 16 + fr;
                const int h = col >> 6, hd = col & 63;
                const int idx = (((b * HH + h) << 10) | t) * HD + hd;
                const float val = acc[m][n][j];
                if (z == 0)      qb[idx] = f2bf(val);
                else if (z == 1) kf[idx] = val;
                else             { vf[idx] = val; vb[idx] = f2bf(val); }
            }
        }
    }
}

// Output projection: y = y_att(bf16) @ Wo^T, f32 out.
__global__ __launch_bounds__(256)
void gemm_out(const short* __restrict__ yab, const float* __restrict__ Wo,
              float* __restrict__ y)
{
    const int row0 = blockIdx.x * 128, col0 = blockIdx.y * 128;
    f32x4 acc[4][4];
#pragma unroll
    for (int m = 0; m < 4; ++m)
#pragma unroll
        for (int n = 0; n < 4; ++n) acc[m][n] = (f32x4){0.f, 0.f, 0.f, 0.f};

    gemm_core<true>(yab, Wo, row0, col0, acc);

    const int lane = threadIdx.x & 63, wid = threadIdx.x >> 6;
    const int fr = lane & 15, fg = lane >> 4;
#pragma unroll
    for (int m = 0; m < 4; ++m)
#pragma unroll
        for (int j = 0; j < 4; ++j) {
            const int row = row0 + (wid >> 1) * 64 + m * 16 + fg * 4 + j;
#pragma unroll
            for (int n = 0; n < 4; ++n) {
                const int col = col0 + (wid & 1) * 64 + n * 16 + fr;
                y[(size_t)row * CC + col] = acc[m][n][j];
            }
        }
}

// ---------------------------------------------------------------------------
// RoPE + QK-RMSNorm. Wave per (b,h,t) row, head dim = lanes.
// q: bf16 in/out (ws), fold score scale 1/8 into q.
// k: f32 in/out (d_out) + bf16 copy to ws for attention.
// ---------------------------------------------------------------------------
__global__ __launch_bounds__(256)
void rope_qknorm(short* __restrict__ qb, float* __restrict__ kf,
                 short* __restrict__ kb)
{
    const int row  = blockIdx.x * 4 + (threadIdx.x >> 6);
    const int lane = threadIdx.x & 63;
    const int t    = row & (TT - 1);

    float qv = bf2f(qb[row * HD + lane]);
    float kv = kf[row * HD + lane];

    const int d = lane & 31;
    const float fr = (float)t * powf(10000.f, -(float)d * (1.f / 32.f));
    const float c = cosf(fr), s = sinf(fr);

    const float qp = __shfl_xor(qv, 32);
    const float kp = __shfl_xor(kv, 32);

    float qo, ko;
    if (lane < 32) { qo = qv * c - qp * s;  ko = kv * c - kp * s; }
    else           { qo = qp * s + qv * c;  ko = kp * s + kv * c; }

    float qs = qo * qo, ks = ko * ko;
#pragma unroll
    for (int m = 1; m < 64; m <<= 1) {
        qs += __shfl_xor(qs, m);
        ks += __shfl_xor(ks, m);
    }
    qo *= rsqrtf(qs * (1.f / 64.f) + 1e-6f);
    ko *= rsqrtf(ks * (1.f / 64.f) + 1e-6f);

    qb[row * HD + lane] = f2bf(qo * 0.125f);   // fold 1/sqrt(Hd)
    kf[row * HD + lane] = ko;
    kb[row * HD + lane] = f2bf(ko);
}

// ---------------------------------------------------------------------------
// MFMA flash attention. Block = 256 thr = 4 waves, one (b,h), 64 Q rows
// (wave w owns rows q0 = qt*64 + w*16 .. +15, Q frags in registers).
// Per 32-key tile: QK^T (2 n-slices x 2 k-slices MFMA), wave-parallel online
// softmax (rows live in 16-lane groups, shfl_xor 1/2/4/8), P -> per-wave LDS
// (bf16), PV (4 MFMA vs transposed-V LDS tile).
// ---------------------------------------------------------------------------
__global__ __launch_bounds__(256)
void attn_mfma(const short* __restrict__ qb, const short* __restrict__ kb,
               const short* __restrict__ vb, short* __restrict__ yab)
{
    __shared__ short Ks[32][72];     // [key][hd], stride 144B
    __shared__ short Vt[64][40];     // [hd][key], stride 80B
    __shared__ short Ps[4][16][40];  // per wave: [qrow][key]

    const int qt   = 15 - blockIdx.x;      // big tiles first
    const int bh   = blockIdx.y;           // 0..95
    const int tid  = threadIdx.x;
    const int lane = tid & 63, wid = tid >> 6;
    const int fr   = lane & 15, fg = lane >> 4;
    const int q0   = qt * 64 + wid * 16;

    const short* qbase = qb + (size_t)(bh << 10) * HD;
    const short* kbase = kb + (size_t)(bh << 10) * HD;
    const short* vbase = vb + (size_t)(bh << 10) * HD;

    // Q fragments (rows q0+fr, k-slices hd 0-31 / 32-63), already scaled
    bf16x8 aq[2];
#pragma unroll
    for (int ks = 0; ks < 2; ++ks)
        aq[ks] = *(const bf16x8*)&qbase[(q0 + fr) * HD + ks * 32 + fg * 8];

    f32x4 acc[4];
#pragma unroll
    for (int n = 0; n < 4; ++n) acc[n] = (f32x4){0.f, 0.f, 0.f, 0.f};
    float mrow[4] = {-1e30f, -1e30f, -1e30f, -1e30f};
    float lrow[4] = {0.f, 0.f, 0.f, 0.f};

    const int ktend = 2 * qt + 2;
    for (int kt = 0; kt < ktend; ++kt) {
        __syncthreads();
        {   // stage K [32][64] row-major: one 16B chunk per thread
            const int key = tid >> 3, c8 = (tid & 7) * 8;
            *(int4*)&Ks[key][c8] =
                *(const int4*)&kbase[(kt * 32 + key) * HD + c8];
            // stage V transposed: thread reads V[key][h8..h8+7], scatters rows
            const int vkey = tid & 31, h8 = (tid >> 5) * 8;
            const int4 vraw = *(const int4*)&vbase[(kt * 32 + vkey) * HD + h8];
            const short* vp = (const short*)&vraw;
#pragma unroll
            for (int i = 0; i < 8; ++i) Vt[h8 + i][vkey] = vp[i];
        }
        __syncthreads();

        // S = Q K^T : D rows = q (fg*4+j), cols = key (fr)
        f32x4 s[2];
#pragma unroll
        for (int ns = 0; ns < 2; ++ns) {
            const bf16x8 bk0 = *(const bf16x8*)&Ks[ns * 16 + fr][fg * 8];
            const bf16x8 bk1 = *(const bf16x8*)&Ks[ns * 16 + fr][32 + fg * 8];
            f32x4 z = (f32x4){0.f, 0.f, 0.f, 0.f};
            z = __builtin_amdgcn_mfma_f32_16x16x32_bf16(aq[0], bk0, z, 0, 0, 0);
            z = __builtin_amdgcn_mfma_f32_16x16x32_bf16(aq[1], bk1, z, 0, 0, 0);
            s[ns] = z;
        }

        // online softmax per owned row j
#pragma unroll
        for (int j = 0; j < 4; ++j) {
            const int q = q0 + fg * 4 + j;
            const int kc0 = kt * 32 + fr, kc1 = kc0 + 16;
            float s0 = (kc0 <= q) ? s[0][j] : -1e30f;
            float s1 = (kc1 <= q) ? s[1][j] : -1e30f;
            float cm = fmaxf(s0, s1);
            cm = fmaxf(cm, __shfl_xor(cm, 1));
            cm = fmaxf(cm, __shfl_xor(cm, 2));
            cm = fmaxf(cm, __shfl_xor(cm, 4));
            cm = fmaxf(cm, __shfl_xor(cm, 8));
            const float mnew = fmaxf(mrow[j], cm);
            const float f = __expf(mrow[j] - mnew);
            const float p0 = __expf(s0 - mnew);
            const float p1 = __expf(s1 - mnew);
            float rs = p0 + p1;
            rs += __shfl_xor(rs, 1);
            rs += __shfl_xor(rs, 2);
            rs += __shfl_xor(rs, 4);
            rs += __shfl_xor(rs, 8);
            lrow[j] = lrow[j] * f + rs;
            mrow[j] = mnew;
            acc[0][j] *= f; acc[1][j] *= f; acc[2][j] *= f; acc[3][j] *= f;
            Ps[wid][fg * 4 + j][fr]      = f2bf(p0);
            Ps[wid][fg * 4 + j][16 + fr] = f2bf(p1);
        }
        __syncthreads();

        // O += P V : A = P[fr][fg*8..+7], B = Vt[hd n*16+fr][keys fg*8..+7]
        const bf16x8 pa = *(const bf16x8*)&Ps[wid][fr][fg * 8];
#pragma unroll
        for (int n = 0; n < 4; ++n) {
            const bf16x8 vfr = *(const bf16x8*)&Vt[n * 16 + fr][fg * 8];
            acc[n] = __builtin_amdgcn_mfma_f32_16x16x32_bf16(pa, vfr, acc[n], 0, 0, 0);
        }
    }

    // epilogue: y_att (B,T,C) bf16
    const int b = bh / HH, h = bh % HH;
#pragma unroll
    for (int j = 0; j < 4; ++j) {
        const int q = q0 + fg * 4 + j;
        const float inv = 1.f / lrow[j];
#pragma unroll
        for (int n = 0; n < 4; ++n)
            yab[(size_t)(b * TT + q) * CC + h * HD + n * 16 + fr] =
                f2bf(acc[n][j] * inv);
    }
}

// ---------------------------------------------------------------------------
extern "C" void kernel_launch(void* const* d_in, const int* in_sizes, int n_in,
                              void* d_out, int out_size, void* d_ws, size_t ws_size,
                              hipStream_t stream)
{
    (void)in_sizes; (void)n_in; (void)out_size; (void)ws_size;
    const float* x  = (const float*)d_in[0];
    const float* Wq = (const float*)d_in[1];
    const float* Wk = (const float*)d_in[2];
    const float* Wv = (const float*)d_in[3];
    const float* Wo = (const float*)d_in[4];

    float* y_out = (float*)d_out;            // (B,T,C) f32
    float* k_out = y_out + NELT;             // (B,H,T,Hd) f32
    float* v_out = k_out + NELT;             // (B,H,T,Hd) f32

    short* qb  = (short*)d_ws;               // bf16 q  (B,H,T,Hd)
    short* kb  = qb + NELT;                  // bf16 k
    short* vb  = kb + NELT;                  // bf16 v
    short* yab = vb + NELT;                  // bf16 attention out (B,T,C)
                                             // total ws = 8*NELT bytes = 50.3MB

    gemm_qkv<<<dim3(MM/128, CC/128, 3), 256, 0, stream>>>(x, Wq, Wk, Wv,
                                                          qb, k_out, v_out, vb);
    rope_qknorm<<<dim3((BB*HH*TT)/4), 256, 0, stream>>>(qb, k_out, kb);
    attn_mfma<<<dim3(TT/64, BB*HH), 256, 0, stream>>>(qb, kb, vb, yab);
    gemm_out<<<dim3(MM/128, CC/128), 256, 0, stream>>>(yab, Wo, y_out);
}